// Round 15
// baseline (54.169 us; speedup 1.0000x reference)
//
#include <hip/hip_runtime.h>
#include <hip/hip_bf16.h>

// InfoNCE loss, B=8, N=2048, D=256, T=0.1 — THREE kernels:
//  gather3: fused mask prefix-scan (r13-verified per-wave popcount) +
//           L2-normalize -> compacted bf16 zc; block rr==511 writes mcnt +
//           gc pad sentinels + zeroes global accumulators.
//  main:    r14's counted-vmcnt 3-buffer loop, DUAL row-tile waves
//           (BROWS=128: each bfrag read feeds 2 MFMAs -> LDS traffic halves).
//  finalize: per-row log-ratio + done-ticket scalar write.
// ws layout (~12 MB):
//   [0]       float gsum[16] (0: loss sum, 1: count)
//   [64]      int   done
//   [128]     int   mcnt[B]
//   [2048]    int   gc[B][2048]       compacted groups (pad = 0x10000)
//   [69632]   ushort zc[B][2048][256] compacted bf16-normalized rows
//   [8458240] float pd[NCH][B][2048]  per-chunk denom partials
//   [8982528] float pn[NCH][B][2048]  per-chunk numer partials

#define B_ 8
#define N_ 2048
#define D_ 256
#define NCH 8      // column-tile chunks (tile t -> chunk t%NCH)
#define BROWS 128  // rows per block = 4 waves x 2 row-tiles x 16 rows
#define TCOLS 16   // columns per LDS tile (8 KB); 3 bufs = 24 KB
#define TILEB (TCOLS * 512)
#define NEGB -16384.0f

typedef __attribute__((ext_vector_type(8))) short bf16x8;
typedef __attribute__((ext_vector_type(4))) float f32x4;

__device__ __forceinline__ void gload16(const void* g, void* l) {
  __builtin_amdgcn_global_load_lds(
      (const __attribute__((address_space(1))) void*)g,
      (__attribute__((address_space(3))) void*)l, 16, 0, 0);
}

// Fused scan+gather. 1D grid B*512, b = lin&7 (XCD-local). Wave w owns
// original row i = (lin>>3)*4 + w: per-lane popcount gives prefix (below)
// and batch total; masked-in rows are normalized into compacted slot zc[pos].
// Block rr==511 (has total) writes mcnt, gc pad sentinels, and global init.
__global__ void gather3_kernel(const float* __restrict__ emb,
                               const int* __restrict__ groups,
                               const void* __restrict__ maskRaw,
                               int* __restrict__ gc, int* __restrict__ mcnt,
                               unsigned short* __restrict__ zc,
                               float* gsum, int* done) {
  const int lin = blockIdx.x;
  const int b = lin & 7;
  const int rr = lin >> 3;  // 0..511
  const int tid = threadIdx.x;
  const int w = tid >> 6, l = tid & 63;
  const int i = rr * 4 + w;  // original row this wave owns

  // dtype detect over first 16KB (in-bounds for both bool and int32)
  __shared__ int cnt_s;
  if (tid == 0) cnt_s = 0;
  __syncthreads();
  {
    const int4* p4 = (const int4*)maskRaw;
    int c = 0;
    for (int q = tid; q < 1024; q += 256) {
      const int4 v = p4[q];
      c += ((v.x & 0xFFFFFF00) != 0) + ((v.y & 0xFFFFFF00) != 0) +
           ((v.z & 0xFFFFFF00) != 0) + ((v.w & 0xFFFFFF00) != 0);
    }
    atomicAdd(&cnt_s, c);
  }
  __syncthreads();
  const bool isInt = (cnt_s == 0);  // int32 0/1 values: upper bytes all zero

  // per-wave prefix: below = popcount mask[0..i), total = popcount mask[0..N)
  int below = 0, total = 0;
  if (isInt) {
    const int* mi = (const int*)maskRaw + b * N_;
    const int4* p = (const int4*)mi + l * 8;  // lane covers ints [32l, 32l+32)
#pragma unroll
    for (int c = 0; c < 8; c++) {
      const int4 v = p[c];
      const int bs = l * 32 + c * 4;
      const int n0 = (v.x != 0), n1 = (v.y != 0), n2 = (v.z != 0), n3 = (v.w != 0);
      total += n0 + n1 + n2 + n3;
      below += (bs + 0 < i ? n0 : 0) + (bs + 1 < i ? n1 : 0) +
               (bs + 2 < i ? n2 : 0) + (bs + 3 < i ? n3 : 0);
    }
  } else {
    const unsigned char* mb = (const unsigned char*)maskRaw + b * N_;
    const int4* p = (const int4*)mb + l * 2;  // lane covers bytes [32l, 32l+32)
#pragma unroll
    for (int c = 0; c < 2; c++) {
      const int4 v = p[c];
      const int dw[4] = {v.x, v.y, v.z, v.w};
#pragma unroll
      for (int q = 0; q < 4; q++) {
        int x = dw[q];
        x |= x >> 4; x |= x >> 2; x |= x >> 1;
        const int nz01 = x & 0x01010101;  // LSB of each byte = byte != 0
        total += __popc(nz01);
        const int bs = l * 32 + c * 16 + q * 4;
        const int rem = i - bs;
        const int mm = (rem >= 4) ? nz01
                     : ((rem <= 0) ? 0 : (nz01 & ((1 << (8 * rem)) - 1)));
        below += __popc(mm);
      }
    }
  }
#pragma unroll
  for (int s = 1; s < 64; s <<= 1) {
    below += __shfl_xor(below, s);
    total += __shfl_xor(total, s);
  }

  // gather + normalize masked-in row into compacted slot
  const bool mk = isInt ? (((const int*)maskRaw)[b * N_ + i] != 0)
                        : (((const unsigned char*)maskRaw)[b * N_ + i] != 0);
  if (mk) {
    const int pos = below;
    const float4 v = *(const float4*)(emb + ((size_t)b * N_ + i) * D_ + l * 4);
    float ss = v.x * v.x + v.y * v.y + v.z * v.z + v.w * v.w;
#pragma unroll
    for (int s = 1; s < 64; s <<= 1) ss += __shfl_xor(ss, s);
    const float inv = 1.f / fmaxf(sqrtf(ss), 1e-12f);
    union { ushort4 u; __hip_bfloat162 h[2]; } pck;
    pck.h[0] = __float22bfloat162_rn(float2{v.x * inv, v.y * inv});
    pck.h[1] = __float22bfloat162_rn(float2{v.z * inv, v.w * inv});
    *(ushort4*)(zc + ((size_t)b * N_ + pos) * D_ + l * 4) = pck.u;
    if (l == 0) gc[b * N_ + pos] = groups[b * N_ + i];
  }

  // block rr==511: mcnt + pad sentinels (gc only; zc pads stay garbage —
  // finite bf16, forced to e=0 by the sentinel) + global init
  if (rr == 511) {
    if (tid == 0) mcnt[b] = total;
    const int mpad = (total + 63) & ~63;
    const int k = total + tid;
    if (k < mpad) gc[b * N_ + k] = 0x10000;
    if (b == 0 && tid == 0) { gsum[0] = 0.f; gsum[1] = 0.f; *done = 0; }
  }
}

// 1D grid B*8*16, b = lin&7, y = rr&7 (chunk), x = rr>>3 (128-row block).
// 4 waves x 2 row-tiles x 16 rows = 128 rows; 16-col tiles ct = y, y+NCH, ...
// in a 3-buffer rotation with counted vmcnt (2 tiles in flight). Each bfrag
// ds_read feeds TWO MFMAs (acc0/acc1) -> LDS traffic per FLOP halves.
__global__ __launch_bounds__(256, 4) void main_kernel(
    const unsigned short* __restrict__ zc, const int* __restrict__ gc,
    const int* __restrict__ mcnt, float* __restrict__ pd, float* __restrict__ pn) {
  __shared__ unsigned short colZ[3][TCOLS * 256];  // 3 x 8 KB
  __shared__ int gjAll[256];                       // gj per (tile it, col)

  const unsigned lin = blockIdx.x;
  const int b = lin & 7;
  const int rr = lin >> 3;     // 0..127
  const int y = rr & 7;        // chunk 0..7
  const int x = rr >> 3;       // row-block 0..15
  const int m = mcnt[b];
  const int rowBase = x * BROWS;
  if (rowBase >= m) return;
  const int ntiles = (m + TCOLS - 1) / TCOLS;  // 16-col tiles
  const int nt = (y < ntiles) ? ((ntiles - y + NCH - 1) / NCH) : 0;
  if (nt <= 0) return;

  const int tid = threadIdx.x;
  const int w = tid >> 6, l = tid & 63, l15 = l & 15, lg = l >> 4;
  const unsigned short* zb = zc + (size_t)b * N_ * D_;
  const int* gb = gc + b * N_;

  // per-lane pre-swizzled source offset (involution: LDS[L] = G[L ^ ((row&7)<<4)])
  const int srcOff = (tid * 16) ^ (((tid >> 5) & 7) << 4);
  const int ldsOff = tid * 16;

#define STAGE(buf, ctv)                                                        \
  {                                                                            \
    const char* _s = (const char*)zb + (size_t)(ctv) * TILEB + srcOff;         \
    char* _l = (char*)colZ + (buf) * TILEB + ldsOff;                           \
    gload16(_s, _l);                                                           \
    gload16(_s + 4096, _l + 4096);                                             \
  }

  // ---- prologue (fully drained by __syncthreads at the end) ----
  STAGE(0, y);
  if (nt > 1) STAGE(1, y + NCH);
  {  // pre-stage gj for up to 16 tiles of this chunk
    const int t = tid >> 4;
    if (t < nt) gjAll[tid] = gb[(y + t * NCH) * TCOLS + (tid & 15)];
  }
  // A fragments: lane holds row (l&15) of each 16-row tile, k = kt*32+lg*8+e
  bf16x8 afrag[2][8];
#pragma unroll
  for (int t2 = 0; t2 < 2; t2++) {
    const int arow = rowBase + w * 32 + t2 * 16 + l15;
#pragma unroll
    for (int kt = 0; kt < 8; kt++)
      afrag[t2][kt] = *(const bf16x8*)(zb + (size_t)arow * D_ + kt * 32 + lg * 8);
  }

  int irow[2][4], gi[2][4];
#pragma unroll
  for (int t2 = 0; t2 < 2; t2++)
#pragma unroll
    for (int r = 0; r < 4; r++) {
      irow[t2][r] = rowBase + w * 32 + t2 * 16 + lg * 4 + r;  // C/D row map
      gi[t2][r] = gb[irow[t2][r]];
    }

  float dP[2][4] = {{0.f, 0.f, 0.f, 0.f}, {0.f, 0.f, 0.f, 0.f}};
  float nP[2][4] = {{0.f, 0.f, 0.f, 0.f}, {0.f, 0.f, 0.f, 0.f}};

  __syncthreads();  // full drain once: tiles 0(,1) + gjAll + afrag all landed

  // ---- main loop: counted vmcnt, loads 2 tiles ahead ----
  for (int it = 0; it < nt; it++) {
    const int ct = y + it * NCH;
    if (it < nt - 1) {
      asm volatile("s_waitcnt vmcnt(2)" ::: "memory");  // tile it landed
    } else {
      asm volatile("s_waitcnt vmcnt(0)" ::: "memory");
    }
    __builtin_amdgcn_s_barrier();  // all waves' tile-it loads complete
    if (it + 2 < nt) STAGE((it + 2) % 3, ct + 2 * NCH);
    const bool diagT = ((ct >> 3) == x);  // 16-col tile inside 128-row block?
    const char* bufc = (const char*)colZ + (it % 3) * TILEB;
    {
      f32x4 acc0 = {0.f, 0.f, 0.f, 0.f};
      f32x4 acc1 = {0.f, 0.f, 0.f, 0.f};
      const char* bbase = bufc + l15 * 512;
      const int bx = (l15 & 7) << 4;
#pragma unroll
      for (int kt = 0; kt < 8; kt++) {
        const bf16x8 bfrag = *(const bf16x8*)(bbase + ((lg * 16 + kt * 64) ^ bx));
        acc0 = __builtin_amdgcn_mfma_f32_16x16x32_bf16(afrag[0][kt], bfrag, acc0, 0, 0, 0);
        acc1 = __builtin_amdgcn_mfma_f32_16x16x32_bf16(afrag[1][kt], bfrag, acc1, 0, 0, 0);
      }
      const int j = ct * TCOLS + l15;
      const int gj = gjAll[it * 16 + l15];             // LDS (lgkm), no VM op
      const float bias = (gj & 0x10000) ? NEGB : 0.f;  // pad col -> exp == 0
#pragma unroll
      for (int r = 0; r < 4; r++) {
        float a0 = bias, a1 = bias;
        if (diagT) {
          if (j == irow[0][r]) a0 = NEGB;  // exclude diagonal
          if (j == irow[1][r]) a1 = NEGB;
        }
        const float e0 = __builtin_exp2f(fmaf(acc0[r], 14.4269504089f, a0));
        const float e1 = __builtin_exp2f(fmaf(acc1[r], 14.4269504089f, a1));
        dP[0][r] += e0;
        dP[1][r] += e1;
        if (gj == gi[0][r]) nP[0][r] += e0;
        if (gj == gi[1][r]) nP[1][r] += e1;
      }
    }
  }

  // reduce over the 16-lane column axis; lane l15==0 owns the row
#pragma unroll
  for (int t2 = 0; t2 < 2; t2++)
#pragma unroll
    for (int r = 0; r < 4; r++) {
      float d = dP[t2][r], n = nP[t2][r];
#pragma unroll
      for (int mm = 1; mm < 16; mm <<= 1) {
        d += __shfl_xor(d, mm);
        n += __shfl_xor(n, mm);
      }
      if (l15 == 0) {
        const int row = rowBase + w * 32 + t2 * 16 + lg * 4 + r;
        const size_t o = ((size_t)y * B_ + b) * N_ + row;  // [chunk][b][row]
        pd[o] = d;
        pn[o] = n;
      }
    }
#undef STAGE
}

// Per compacted row: loss contribution; fused final division via done-counter.
__global__ void finalize_kernel(const float* __restrict__ pd, const float* __restrict__ pn,
                                const int* __restrict__ mcnt, float* gsum, int* done,
                                float* out) {
  const int g = blockIdx.x * 256 + threadIdx.x;
  const int b = g >> 11, k = g & (N_ - 1);
  const int m = mcnt[b];
  float contrib = 0.f, cnt = 0.f;
  if (k < m) {
    const int nch = min(NCH, (m + TCOLS - 1) / TCOLS);
    float d = 0.f, n = 0.f;
    for (int c = 0; c < nch; c++) {
      d += pd[((size_t)c * B_ + b) * N_ + k];
      n += pn[((size_t)c * B_ + b) * N_ + k];
    }
    if (n > 0.f) {
      contrib = __logf(d) - __logf(n);  // -log(numer/denom)
      cnt = 1.f;
    }
  }
#pragma unroll
  for (int s = 1; s < 64; s <<= 1) {
    contrib += __shfl_xor(contrib, s);
    cnt += __shfl_xor(cnt, s);
  }
  __shared__ float sc[4], sn[4];
  __shared__ bool isLast;
  const int w = threadIdx.x >> 6;
  if ((threadIdx.x & 63) == 0) { sc[w] = contrib; sn[w] = cnt; }
  __syncthreads();
  if (threadIdx.x == 0) {
    atomicAdd(&gsum[0], sc[0] + sc[1] + sc[2] + sc[3]);
    atomicAdd(&gsum[1], sn[0] + sn[1] + sn[2] + sn[3]);
    __threadfence();
    isLast = (atomicAdd(done, 1) == (int)gridDim.x - 1);
  }
  __syncthreads();
  if (isLast && threadIdx.x == 0) {
    const float s = atomicAdd(&gsum[0], 0.f);  // coherent read
    const float c = atomicAdd(&gsum[1], 0.f);
    out[0] = (c > 0.f) ? s / fmaxf(c, 1.f) : 0.f;
  }
}

extern "C" void kernel_launch(void* const* d_in, const int* in_sizes, int n_in,
                              void* d_out, int out_size, void* d_ws, size_t ws_size,
                              hipStream_t stream) {
  const float* emb = (const float*)d_in[0];
  const int* groups = (const int*)d_in[1];
  const void* mask = d_in[2];
  float* out = (float*)d_out;

  char* ws = (char*)d_ws;
  float* gsum = (float*)ws;
  int* done = (int*)(ws + 64);
  int* mcnt = (int*)(ws + 128);
  int* gc = (int*)(ws + 2048);
  unsigned short* zc = (unsigned short*)(ws + 69632);
  float* pd = (float*)(ws + 8458240);
  float* pn = (float*)(ws + 8982528);

  gather3_kernel<<<B_ * 512, 256, 0, stream>>>(emb, groups, mask, gc, mcnt, zc,
                                               gsum, done);
  main_kernel<<<B_ * 8 * 16, 256, 0, stream>>>(zc, gc, mcnt, pd, pn);
  finalize_kernel<<<(B_ * N_) / 256, 256, 0, stream>>>(pd, pn, mcnt, gsum, done, out);
}

// Round 16
// 36.681 us; speedup vs baseline: 1.4768x; 1.4768x over previous
//
#include <hip/hip_runtime.h>
#include <hip/hip_bf16.h>

// InfoNCE loss, B=8, N=2048, D=256, T=0.1 — mask-compacted, XCD-local,
// counted-vmcnt triple-buffered main with CU-spread decode (r14, session
// best: 36.2 us). Pure revert of r15's regression (dual-tile halved the
// active block count to 2/CU; blocks/CU is the latency-hiding lever).
// ws layout (~9.6 MB): same as r8/r11/r14.

#define B_ 8
#define N_ 2048
#define D_ 256
#define NCH 8     // column-tile chunks (tile t -> chunk t%NCH)
#define BROWS 64  // rows per block = 4 waves x 16 rows
#define TCOLS 16  // columns per LDS tile (8 KB); 3 bufs = 24 KB -> 6 blocks/CU
#define TILEB (TCOLS * 512)
#define NEGB -16384.0f

typedef __attribute__((ext_vector_type(8))) short bf16x8;
typedef __attribute__((ext_vector_type(4))) float f32x4;

__device__ __forceinline__ void gload16(const void* g, void* l) {
  __builtin_amdgcn_global_load_lds(
      (const __attribute__((address_space(1))) void*)g,
      (__attribute__((address_space(3))) void*)l, 16, 0, 0);
}

// One block per batch: detect mask dtype, prefix-scan mask, emit compacted
// index list + compacted groups (+sentinel pad), per-batch count. Block 0
// also zeroes the global accumulators.
__global__ void scan_kernel(const void* __restrict__ maskRaw, const int* __restrict__ groups,
                            int* __restrict__ idx, int* __restrict__ gc,
                            int* __restrict__ mcnt, float* gsum, int* done) {
  const int b = blockIdx.x, tid = threadIdx.x;
  __shared__ int cnt_s;
  __shared__ int warpOff[4];
  if (tid == 0) cnt_s = 0;
  __syncthreads();
  // dtype detect over first 16KB (in-bounds for both bool and int32)
  const int4* p4 = (const int4*)maskRaw;
  int c = 0;
  for (int i = tid; i < 1024; i += 256) {
    const int4 v = p4[i];
    c += ((v.x & 0xFFFFFF00) != 0) + ((v.y & 0xFFFFFF00) != 0) +
         ((v.z & 0xFFFFFF00) != 0) + ((v.w & 0xFFFFFF00) != 0);
  }
  atomicAdd(&cnt_s, c);
  __syncthreads();
  const bool isInt = (cnt_s == 0);  // int32 0/1 values: upper bytes all zero

  unsigned int bits = 0;
  if (isInt) {
    const int* ip = (const int*)maskRaw + b * N_ + tid * 8;
#pragma unroll
    for (int e = 0; e < 8; e++) bits |= (unsigned)(ip[e] != 0) << e;
  } else {
    const unsigned char* bp = (const unsigned char*)maskRaw + b * N_ + tid * 8;
#pragma unroll
    for (int e = 0; e < 8; e++) bits |= (unsigned)(bp[e] != 0) << e;
  }
  const int myc = __popc(bits);
  int pre = myc;
#pragma unroll
  for (int s = 1; s < 64; s <<= 1) {
    const int t = __shfl_up(pre, s);
    if ((tid & 63) >= s) pre += t;
  }
  const int w = tid >> 6;
  if ((tid & 63) == 63) warpOff[w] = pre;
  __syncthreads();
  int wbase = 0;
#pragma unroll
  for (int ww = 0; ww < 4; ww++) wbase += (ww < w) ? warpOff[ww] : 0;
  int pos = wbase + pre - myc;  // exclusive prefix
  const int m = warpOff[0] + warpOff[1] + warpOff[2] + warpOff[3];

  const int* gp = groups + b * N_;
#pragma unroll
  for (int e = 0; e < 8; e++) {
    if (bits & (1u << e)) {
      const int i = tid * 8 + e;
      idx[b * N_ + pos] = i;
      gc[b * N_ + pos] = gp[i];
      pos++;
    }
  }
  if (tid == 0) mcnt[b] = m;
  const int mpad = (m + 63) & ~63;
  if (tid < 64 && m + tid < mpad) gc[b * N_ + m + tid] = 0x10000;  // pad sentinel
  if (b == 0 && tid == 0) { gsum[0] = 0.f; gsum[1] = 0.f; *done = 0; }
}

// One wave per compacted row: gather emb[idx[k]], L2-normalize, bf16 -> zc.
// XCD-swizzled so zc[b] is written (and cached) on XCD b.
__global__ void gather_kernel(const float* __restrict__ emb, const int* __restrict__ idx,
                              const int* __restrict__ mcnt, unsigned short* __restrict__ zc) {
  const unsigned lin = blockIdx.x;
  const int b = lin & 7;
  const int rr = lin >> 3;  // 0..511
  const int w = threadIdx.x >> 6, l = threadIdx.x & 63;
  const int k = rr * 4 + w;
  const int m = mcnt[b];
  const int mpad = (m + 63) & ~63;
  if (k >= mpad) return;
  ushort4 o = {0, 0, 0, 0};
  if (k < m) {
    const int i = idx[b * N_ + k];
    const float4 v = *(const float4*)(emb + ((size_t)b * N_ + i) * D_ + l * 4);
    float ss = v.x * v.x + v.y * v.y + v.z * v.z + v.w * v.w;
#pragma unroll
    for (int s = 1; s < 64; s <<= 1) ss += __shfl_xor(ss, s);
    const float inv = 1.f / fmaxf(sqrtf(ss), 1e-12f);
    union { ushort4 u; __hip_bfloat162 h[2]; } p;
    p.h[0] = __float22bfloat162_rn(float2{v.x * inv, v.y * inv});
    p.h[1] = __float22bfloat162_rn(float2{v.z * inv, v.w * inv});
    o = p.u;
  }
  *(ushort4*)(zc + ((size_t)b * N_ + k) * D_ + l * 4) = o;
}

// 1D grid, b = lin&7 (XCD-local), y = rr&7, x = rr>>3 (CU-spread decode).
// 4 waves x 16 rows = 64 compacted rows per block; 16-col tiles ct = y,
// y+NCH, ... in a 3-buffer rotation, 2 tiles of loads in flight; per-tile
// sync = s_waitcnt vmcnt(2) + raw s_barrier (counted-vmcnt T4 pattern).
// gj values pre-staged to LDS so the loop has NO other VM ops.
__global__ __launch_bounds__(256, 6) void main_kernel(
    const unsigned short* __restrict__ zc, const int* __restrict__ gc,
    const int* __restrict__ mcnt, float* __restrict__ pd, float* __restrict__ pn) {
  __shared__ unsigned short colZ[3][TCOLS * 256];  // 3 x 8 KB
  __shared__ int gjAll[256];                       // gj per (tile it, col)

  const unsigned lin = blockIdx.x;
  const int b = lin & 7;
  const int rr = lin >> 3;     // 0..255
  const int y = rr & 7;        // chunk 0..7   (CU-spread: active x -> all CUs)
  const int x = rr >> 3;       // row-block 0..31
  const int m = mcnt[b];
  const int rowBase = x * BROWS;
  if (rowBase >= m) return;
  const int ntiles = (m + TCOLS - 1) / TCOLS;  // 16-col tiles
  const int nt = (y < ntiles) ? ((ntiles - y + NCH - 1) / NCH) : 0;
  if (nt <= 0) return;

  const int tid = threadIdx.x;
  const int w = tid >> 6, l = tid & 63, l15 = l & 15, lg = l >> 4;
  const unsigned short* zb = zc + (size_t)b * N_ * D_;
  const int* gb = gc + b * N_;

  // per-lane pre-swizzled source offset (involution: LDS[L] = G[L ^ ((row&7)<<4)])
  const int srcOff = (tid * 16) ^ (((tid >> 5) & 7) << 4);
  const int ldsOff = tid * 16;

#define STAGE(buf, ctv)                                                        \
  {                                                                            \
    const char* _s = (const char*)zb + (size_t)(ctv) * TILEB + srcOff;         \
    char* _l = (char*)colZ + (buf) * TILEB + ldsOff;                           \
    gload16(_s, _l);                                                           \
    gload16(_s + 4096, _l + 4096);                                             \
  }

  // ---- prologue (fully drained by __syncthreads at the end) ----
  STAGE(0, y);
  if (nt > 1) STAGE(1, y + NCH);
  {  // pre-stage gj for up to 16 tiles of this chunk
    const int t = tid >> 4;
    if (t < nt) gjAll[tid] = gb[(y + t * NCH) * TCOLS + (tid & 15)];
  }
  // A fragment: lane holds row (l&15), k = kt*32 + lg*8 + e
  bf16x8 afrag[8];
  const int arow = rowBase + w * 16 + l15;
#pragma unroll
  for (int kt = 0; kt < 8; kt++)
    afrag[kt] = *(const bf16x8*)(zb + (size_t)arow * D_ + kt * 32 + lg * 8);

  int irow[4], gi[4];
#pragma unroll
  for (int r = 0; r < 4; r++) {
    irow[r] = rowBase + w * 16 + lg * 4 + r;  // C/D row map
    gi[r] = gb[irow[r]];
  }

  float dP[4] = {0.f, 0.f, 0.f, 0.f};
  float nP[4] = {0.f, 0.f, 0.f, 0.f};

  __syncthreads();  // full drain once: tiles 0(,1) + gjAll + afrag all landed

  // ---- main loop: counted vmcnt, loads 2 tiles ahead ----
  for (int it = 0; it < nt; it++) {
    const int ct = y + it * NCH;
    if (it < nt - 1) {
      asm volatile("s_waitcnt vmcnt(2)" ::: "memory");  // tile it landed
    } else {
      asm volatile("s_waitcnt vmcnt(0)" ::: "memory");
    }
    __builtin_amdgcn_s_barrier();  // all waves' tile-it loads complete
    if (it + 2 < nt) STAGE((it + 2) % 3, ct + 2 * NCH);
    const bool diagT = ((ct >> 2) == x);  // 16-col tile inside 64-row block?
    const char* bufc = (const char*)colZ + (it % 3) * TILEB;
    {
      f32x4 acc = {0.f, 0.f, 0.f, 0.f};
      const char* bbase = bufc + l15 * 512;
      const int bx = (l15 & 7) << 4;
#pragma unroll
      for (int kt = 0; kt < 8; kt++) {
        const bf16x8 bfrag = *(const bf16x8*)(bbase + ((lg * 16 + kt * 64) ^ bx));
        acc = __builtin_amdgcn_mfma_f32_16x16x32_bf16(afrag[kt], bfrag, acc, 0, 0, 0);
      }
      const int j = ct * TCOLS + l15;
      const int gj = gjAll[it * 16 + l15];             // LDS (lgkm), no VM op
      const float bias = (gj & 0x10000) ? NEGB : 0.f;  // pad col -> exp == 0
#pragma unroll
      for (int r = 0; r < 4; r++) {
        float a0 = bias;
        if (diagT && j == irow[r]) a0 = NEGB;  // exclude diagonal
        const float e0 = __builtin_exp2f(fmaf(acc[r], 14.4269504089f, a0));
        dP[r] += e0;
        if (gj == gi[r]) nP[r] += e0;
      }
    }
  }

  // reduce over the 16-lane column axis; lane l15==0 owns the row
#pragma unroll
  for (int r = 0; r < 4; r++) {
    float d = dP[r], n = nP[r];
#pragma unroll
    for (int mm = 1; mm < 16; mm <<= 1) {
      d += __shfl_xor(d, mm);
      n += __shfl_xor(n, mm);
    }
    if (l15 == 0) {
      const int row = rowBase + w * 16 + lg * 4 + r;
      const size_t o = ((size_t)y * B_ + b) * N_ + row;  // [chunk][b][row]
      pd[o] = d;
      pn[o] = n;
    }
  }
#undef STAGE
}

// Per compacted row: loss contribution; fused final division via done-counter.
__global__ void finalize_kernel(const float* __restrict__ pd, const float* __restrict__ pn,
                                const int* __restrict__ mcnt, float* gsum, int* done,
                                float* out) {
  const int g = blockIdx.x * 256 + threadIdx.x;
  const int b = g >> 11, k = g & (N_ - 1);
  const int m = mcnt[b];
  float contrib = 0.f, cnt = 0.f;
  if (k < m) {
    const int nch = min(NCH, (m + TCOLS - 1) / TCOLS);
    float d = 0.f, n = 0.f;
    for (int c = 0; c < nch; c++) {
      d += pd[((size_t)c * B_ + b) * N_ + k];
      n += pn[((size_t)c * B_ + b) * N_ + k];
    }
    if (n > 0.f) {
      contrib = __logf(d) - __logf(n);  // -log(numer/denom)
      cnt = 1.f;
    }
  }
#pragma unroll
  for (int s = 1; s < 64; s <<= 1) {
    contrib += __shfl_xor(contrib, s);
    cnt += __shfl_xor(cnt, s);
  }
  __shared__ float sc[4], sn[4];
  __shared__ bool isLast;
  const int w = threadIdx.x >> 6;
  if ((threadIdx.x & 63) == 0) { sc[w] = contrib; sn[w] = cnt; }
  __syncthreads();
  if (threadIdx.x == 0) {
    atomicAdd(&gsum[0], sc[0] + sc[1] + sc[2] + sc[3]);
    atomicAdd(&gsum[1], sn[0] + sn[1] + sn[2] + sn[3]);
    __threadfence();
    isLast = (atomicAdd(done, 1) == (int)gridDim.x - 1);
  }
  __syncthreads();
  if (isLast && threadIdx.x == 0) {
    const float s = atomicAdd(&gsum[0], 0.f);  // coherent read
    const float c = atomicAdd(&gsum[1], 0.f);
    out[0] = (c > 0.f) ? s / fmaxf(c, 1.f) : 0.f;
  }
}

extern "C" void kernel_launch(void* const* d_in, const int* in_sizes, int n_in,
                              void* d_out, int out_size, void* d_ws, size_t ws_size,
                              hipStream_t stream) {
  const float* emb = (const float*)d_in[0];
  const int* groups = (const int*)d_in[1];
  const void* mask = d_in[2];
  float* out = (float*)d_out;

  char* ws = (char*)d_ws;
  float* gsum = (float*)ws;
  int* done = (int*)(ws + 64);
  int* mcnt = (int*)(ws + 128);
  int* idx = (int*)(ws + 192);
  int* gc = (int*)(ws + 65728);
  unsigned short* zc = (unsigned short*)(ws + 131264);
  float* pd = (float*)(ws + 8519872);
  float* pn = (float*)(ws + 9044160);

  scan_kernel<<<B_, 256, 0, stream>>>(mask, groups, idx, gc, mcnt, gsum, done);
  gather_kernel<<<B_ * 512, 256, 0, stream>>>(emb, idx, mcnt, zc);
  main_kernel<<<B_ * 32 * NCH, 256, 0, stream>>>(zc, gc, mcnt, pd, pn);
  finalize_kernel<<<(B_ * N_) / 256, 256, 0, stream>>>(pd, pn, mcnt, gsum, done, out);
}